// Round 4
// baseline (319.481 us; speedup 1.0000x reference)
//
#include <hip/hip_runtime.h>

// Problem constants (fixed by setup_inputs)
constexpr int Bc = 2, Dc = 48, Hc = 512, Wc = 640;
constexpr int HWc = Hc * Wc;

// Tile: 64x16 spatial, 256 threads, 4 consecutive-w pixels per thread.
constexpr int TW = 64, TH = 16, NT = 256;
constexpr int HALO = 4;                       // far taps reach +/-4
constexpr int SW = TW + 2 * HALO;             // 72 (18 float4 per row)
constexpr int SH = TH + 2 * HALO;             // 24
constexpr int PLANE = SW * SH;                // 1728 floats/plane
constexpr int DC = 2;                         // d-planes per barrier interval
constexpr int DSPLIT = 2;                     // d split across blocks
constexpr int DCHUNK = Dc / DSPLIT;           // 24 planes per block
constexpr int NIT = DCHUNK / DC;              // 12 intervals
constexpr int NVEC = DC * PLANE / 4;          // 864 float4 per interval
constexpr int VPT = (NVEC + NT - 1) / NT;     // 4
constexpr int NSC = DC * PLANE;               // 3456 scalars per interval
constexpr int SPT = (NSC + NT - 1) / NT;      // 14

__device__ __forceinline__ int reflect_h(int h) {
    return h < 0 ? -h : (h >= Hc ? 2 * (Hc - 1) - h : h);
}
__device__ __forceinline__ int reflect_w(int w) {
    return w < 0 ? -w : (w >= Wc ? 2 * (Wc - 1) - w : w);
}

// __launch_bounds__(256, 4): VGPR cap 512/4 = 128 so the 68 weight registers
// stay RESIDENT across the whole d-loop (at the default budget the compiler
// rematerialized them -> 18 hidden global reloads per plane per thread).
// Occupancy: 4 waves/SIMD (VGPR) = 4 blocks/CU; LDS 27.6 KB allows 5.
__global__ __launch_bounds__(NT, 4) void dw_kernel(
    const float* __restrict__ ds, const float* __restrict__ dmin,
    const float* __restrict__ dmax, const float* __restrict__ off,
    const float* __restrict__ scale_p, float* __restrict__ out)
{
    __shared__ float sx[2][DC * PLANE];       // double-buffered (27648 B)

    const int bz   = blockIdx.z;              // b*2 + dchunk
    const int b    = bz >> 1;
    const int dch  = bz & 1;
    const int h0   = blockIdx.y * TH;
    const int w0   = blockIdx.x * TW;
    const int tid  = threadIdx.x;
    const int col4 = tid & 15;                // 16 float4-groups across 64 w
    const int row  = tid >> 4;                // 0..15

    const float inv_max = 1.0f / dmax[b];
    const float invd    = 1.0f / (1.0f / dmin[b] - inv_max);
    const float isc2    = 0.5f / scale_p[0];  // folds the 0.5 acc scale

    // Weights -> registers, reused across all 24 d-planes of this chunk.
    // wF[4] absorbs wN[4] (both center taps hit x0) -> 17 live channels = 68 regs.
    float wF[9][4], wN[9][4];
    {
        const float* op = off + (size_t)b * 18 * HWc
                        + (size_t)(h0 + row) * Wc + (w0 + 4 * col4);
        #pragma unroll
        for (int s = 0; s < 9; ++s) {
            float4 vF = *(const float4*)(op + (size_t)s * HWc);
            float4 vN = *(const float4*)(op + (size_t)(s + 9) * HWc);
            wF[s][0] = vF.x; wF[s][1] = vF.y; wF[s][2] = vF.z; wF[s][3] = vF.w;
            wN[s][0] = vN.x; wN[s][1] = vN.y; wN[s][2] = vN.z; wN[s][3] = vN.w;
        }
        #pragma unroll
        for (int j = 0; j < 4; ++j) wF[4][j] += wN[4][j];   // wN[4] dead -> DCE
    }

    const float* dsb  = ds  + ((size_t)b * Dc + dch * DCHUNK) * HWc;
    float*       outb = out + (size_t)b * Dc * HWc
                            + (size_t)(h0 + row) * Wc + (w0 + 4 * col4);
    const int dg0 = dch * DCHUNK;

    // Stencil for one interval: per plane 15 ds_read_b128 feed 4 pixels.
    auto compute = [&](const float* sb, int dglob0) {
        #pragma unroll
        for (int p = 0; p < DC; ++p) {
            // bp -> plane col 4*col4 == pixel col - 4 (16B aligned)
            const float* bp = sb + p * PLANE + (row + HALO) * SW + 4 * col4;
            float q[12], acc[4], x0[4];
            auto ld12 = [&](const float* src) {
                *(float4*)(q)     = *(const float4*)(src);
                *(float4*)(q + 4) = *(const float4*)(src + 4);
                *(float4*)(q + 8) = *(const float4*)(src + 8);
            };
            ld12(bp - 4 * SW);                // far row dy=-4
            #pragma unroll
            for (int j = 0; j < 4; ++j)
                acc[j] = wF[0][j]*q[j] + wF[1][j]*q[4+j] + wF[2][j]*q[8+j];
            ld12(bp - 2 * SW);                // near row dy=-2
            #pragma unroll
            for (int j = 0; j < 4; ++j)
                acc[j] += wN[0][j]*q[2+j] + wN[1][j]*q[4+j] + wN[2][j]*q[6+j];
            ld12(bp);                         // center row: near+far+x0
            #pragma unroll
            for (int j = 0; j < 4; ++j) {
                x0[j] = q[4+j];
                acc[j] += wF[3][j]*q[j]   + wF[4][j]*q[4+j] + wF[5][j]*q[8+j]
                        + wN[3][j]*q[2+j] + wN[5][j]*q[6+j];
            }
            ld12(bp + 2 * SW);                // near row dy=+2
            #pragma unroll
            for (int j = 0; j < 4; ++j)
                acc[j] += wN[6][j]*q[2+j] + wN[7][j]*q[4+j] + wN[8][j]*q[6+j];
            ld12(bp + 4 * SW);                // far row dy=+4
            #pragma unroll
            for (int j = 0; j < 4; ++j)
                acc[j] += wF[6][j]*q[j] + wF[7][j]*q[4+j] + wF[8][j]*q[8+j];

            float4 o; float* po = (float*)&o;
            #pragma unroll
            for (int j = 0; j < 4; ++j) {
                // x1 = |0.5*acc - x0| / scale, clipped to 4
                float x1 = fminf(fabsf(fmaf(-2.0f, x0[j], acc[j])) * isc2, 4.0f);
                // sigmoid(4 - 2*x1) = 1 / (1 + exp2((2*x1-4)*log2e))
                float e = exp2f(fmaf(x1, 2.8853901817f, -5.7707803635f));
                po[j] = __builtin_amdgcn_rcpf(1.0f + e);
            }
            *(float4*)(outb + (size_t)(dglob0 + p) * HWc) = o;
        }
    };

    // w-reflect only touches first/last block column; others vectorize.
    const bool interior = (blockIdx.x > 0) && (blockIdx.x + 1 < gridDim.x);

    if (interior) {
        int vsrc[VPT];                        // d-invariant source offsets
        #pragma unroll
        for (int i = 0; i < VPT; ++i) {
            int vid = tid + i * NT;
            if (vid < NVEC) {
                int p   = vid / (PLANE / 4);
                int rem = vid - p * (PLANE / 4);
                int r   = rem / (SW / 4);
                int j   = rem - r * (SW / 4);
                int hs  = reflect_h(h0 + r - HALO);
                vsrc[i] = p * HWc + hs * Wc + (w0 - HALO + 4 * j);
            } else vsrc[i] = 0;
        }
        float4 pre[VPT];
        auto issue = [&](int d0) {            // loads stay in flight under compute
            const float* dp = dsb + (size_t)d0 * HWc;
            #pragma unroll
            for (int i = 0; i < VPT; ++i) {
                int vid = tid + i * NT;
                if (vid < NVEC) pre[i] = *(const float4*)(dp + vsrc[i]);
            }
        };
        auto commit = [&](float* sb) {
            #pragma unroll
            for (int i = 0; i < VPT; ++i) {
                int vid = tid + i * NT;
                if (vid < NVEC) {
                    float4 v = pre[i], x;
                    x.x = (__builtin_amdgcn_rcpf(v.x) - inv_max) * invd;
                    x.y = (__builtin_amdgcn_rcpf(v.y) - inv_max) * invd;
                    x.z = (__builtin_amdgcn_rcpf(v.z) - inv_max) * invd;
                    x.w = (__builtin_amdgcn_rcpf(v.w) - inv_max) * invd;
                    *(float4*)(sb + vid * 4) = x;
                }
            }
        };
        issue(0);
        commit(sx[0]);
        __syncthreads();
        for (int it = 0; it < NIT; ++it) {
            if (it + 1 < NIT) issue((it + 1) * DC);
            compute(sx[it & 1], dg0 + it * DC);
            if (it + 1 < NIT) commit(sx[(it + 1) & 1]);
            __syncthreads();
        }
    } else {
        int ssrc[SPT];                        // scalar path (w-edge blocks)
        #pragma unroll
        for (int i = 0; i < SPT; ++i) {
            int idx = tid + i * NT;
            if (idx < NSC) {
                int p   = idx / PLANE;
                int rem = idx - p * PLANE;
                int r   = rem / SW;
                int c   = rem - r * SW;
                int hs  = reflect_h(h0 + r - HALO);
                int ws  = reflect_w(w0 + c - HALO);
                ssrc[i] = p * HWc + hs * Wc + ws;
            } else ssrc[i] = 0;
        }
        float pre[SPT];
        auto issue = [&](int d0) {
            const float* dp = dsb + (size_t)d0 * HWc;
            #pragma unroll
            for (int i = 0; i < SPT; ++i) {
                int idx = tid + i * NT;
                if (idx < NSC) pre[i] = dp[ssrc[i]];
            }
        };
        auto commit = [&](float* sb) {
            #pragma unroll
            for (int i = 0; i < SPT; ++i) {
                int idx = tid + i * NT;
                if (idx < NSC)
                    sb[idx] = (__builtin_amdgcn_rcpf(pre[i]) - inv_max) * invd;
            }
        };
        issue(0);
        commit(sx[0]);
        __syncthreads();
        for (int it = 0; it < NIT; ++it) {
            if (it + 1 < NIT) issue((it + 1) * DC);
            compute(sx[it & 1], dg0 + it * DC);
            if (it + 1 < NIT) commit(sx[(it + 1) & 1]);
            __syncthreads();
        }
    }
}

extern "C" void kernel_launch(void* const* d_in, const int* in_sizes, int n_in,
                              void* d_out, int out_size, void* d_ws, size_t ws_size,
                              hipStream_t stream) {
    const float* ds   = (const float*)d_in[0];  // depth_sample [B,D,H,W]
    const float* dmin = (const float*)d_in[1];  // depth_min [B]
    const float* dmax = (const float*)d_in[2];  // depth_max [B]
    const float* off  = (const float*)d_in[3];  // offset [B,18,H,W]
    const float* sc   = (const float*)d_in[4];  // patchmatch_interval_scale
    float* out = (float*)d_out;                 // [B,D,H,W] fp32

    dim3 grid(Wc / TW, Hc / TH, Bc * DSPLIT);   // (10, 32, 4) = 1280 blocks
    dw_kernel<<<grid, NT, 0, stream>>>(ds, dmin, dmax, off, sc, out);
}